// Round 1
// baseline (1124.130 us; speedup 1.0000x reference)
//
#include <hip/hip_runtime.h>
#include <hip/hip_bf16.h>

#define B_ 8
#define C_ 256
#define L_ 1024
#define NH_ 8
#define HD_ 32
#define EPS_ 1e-5f

// ---------------------------------------------------------------------------
// Kernel A: GroupNorm (32 groups of 8 channels) + depthwise conv1d k=3 pad=1
// one block per (b, group); 8*1024 = 8192 elems per block
// ---------------------------------------------------------------------------
__global__ __launch_bounds__(256) void gn_dwconv_kernel(
    const float* __restrict__ x, const float* __restrict__ gamma,
    const float* __restrict__ beta, const float* __restrict__ dw,
    float* __restrict__ h) {
  int blk = blockIdx.x;           // b*32 + g
  int b = blk >> 5, g = blk & 31;
  int t = threadIdx.x;
  __shared__ float hn[8 * L_];    // 32 KB normalized tile
  __shared__ float ws0[4], ws1[4];
  const size_t base = ((size_t)(b * C_ + g * 8)) * L_;

  float s = 0.f, ss = 0.f;
  float vals[32];
#pragma unroll
  for (int i = 0; i < 32; ++i) {
    int e = t + 256 * i;
    float v = x[base + e];
    vals[i] = v;
    s += v; ss += v * v;
  }
  // block reduce (wave64 shuffle, then across 4 waves via LDS)
#pragma unroll
  for (int off = 32; off >= 1; off >>= 1) {
    s  += __shfl_xor(s, off);
    ss += __shfl_xor(ss, off);
  }
  int wave = t >> 6;
  if ((t & 63) == 0) { ws0[wave] = s; ws1[wave] = ss; }
  __syncthreads();
  s  = ws0[0] + ws0[1] + ws0[2] + ws0[3];
  ss = ws1[0] + ws1[1] + ws1[2] + ws1[3];
  float mean = s * (1.f / 8192.f);
  float var = ss * (1.f / 8192.f) - mean * mean;
  float rstd = rsqrtf(var + EPS_);

#pragma unroll
  for (int i = 0; i < 32; ++i) {
    int e = t + 256 * i;
    int c = g * 8 + (e >> 10);        // channel (uniform per i)
    float sc = gamma[c] * rstd;
    hn[e] = (vals[i] - mean) * sc + beta[c];
  }
  __syncthreads();
#pragma unroll
  for (int i = 0; i < 32; ++i) {
    int e = t + 256 * i;
    int l = e & 1023;
    int c = g * 8 + (e >> 10);
    float w0 = dw[c * 3 + 0], w1 = dw[c * 3 + 1], w2 = dw[c * 3 + 2];
    float a = (l > 0) ? hn[e - 1] : 0.f;
    float m = hn[e];
    float z = (l < 1023) ? hn[e + 1] : 0.f;
    h[base + e] = w0 * a + w1 * m + w2 * z;
  }
}

// ---------------------------------------------------------------------------
// Kernel B/D: pointwise conv (1x1) = GEMM y[b,oc,l] = sum_c W[oc,c]*in[b,c,l]
// + bias (+ optional residual). IC fixed at 256.
// Block computes [64 oc x 256 l]; thread = (og = t>>6) x (lt = t&63),
// 16 oc x 4 l accumulators. W staged transposed in LDS (float4 broadcast).
// grid: (L/256, OC/64, B)
// ---------------------------------------------------------------------------
template <bool RESID>
__global__ __launch_bounds__(256) void pconv_kernel(
    const float* __restrict__ in, const float* __restrict__ W,
    const float* __restrict__ bias, const float* __restrict__ resid,
    float* __restrict__ out, int OC) {
  int b = blockIdx.z;
  int oc0 = blockIdx.y * 64;
  int l0 = blockIdx.x * 256;
  int t = threadIdx.x;
  int og = t >> 6, lt = t & 63;
  __shared__ float wsT[64][68];   // [c-chunk][oc-local], pad 68 keeps 16B align

  float acc[16][4];
#pragma unroll
  for (int i = 0; i < 16; ++i)
#pragma unroll
    for (int k = 0; k < 4; ++k) acc[i][k] = 0.f;

  const float* inb = in + (size_t)b * 256 * L_ + l0 + lt;

  for (int c0 = 0; c0 < 256; c0 += 64) {
    __syncthreads();
    for (int id = t; id < 4096; id += 256) {
      int cc = id & 63, ocl = id >> 6;   // coalesced read of W
      wsT[cc][ocl] = W[(size_t)(oc0 + ocl) * 256 + c0 + cc];
    }
    __syncthreads();
    for (int cc = 0; cc < 64; ++cc) {
      float hv[4];
#pragma unroll
      for (int k = 0; k < 4; ++k) hv[k] = inb[(size_t)(c0 + cc) * L_ + 64 * k];
      float wv[16];
      *(float4*)&wv[0]  = *(const float4*)&wsT[cc][og * 16 + 0];
      *(float4*)&wv[4]  = *(const float4*)&wsT[cc][og * 16 + 4];
      *(float4*)&wv[8]  = *(const float4*)&wsT[cc][og * 16 + 8];
      *(float4*)&wv[12] = *(const float4*)&wsT[cc][og * 16 + 12];
#pragma unroll
      for (int i = 0; i < 16; ++i)
#pragma unroll
        for (int k = 0; k < 4; ++k) acc[i][k] += wv[i] * hv[k];
    }
  }

#pragma unroll
  for (int i = 0; i < 16; ++i) {
    int oc = oc0 + og * 16 + i;
    float bs = bias[oc];
    size_t ob = ((size_t)b * OC + oc) * L_ + l0 + lt;
#pragma unroll
    for (int k = 0; k < 4; ++k) {
      float r = acc[i][k] + bs;
      if (RESID) r += resid[ob + 64 * k];
      out[ob + 64 * k] = r;
    }
  }
}

// ---------------------------------------------------------------------------
// Kernel C: attention for one (b, h), 64-row chunk per block, 8 rows per pass.
// qkv layout: [B, 768, L]; q at ch h*96+d, k at h*96+32+d, v at h*96+64+d.
// grid: (16, B*NH)
// ---------------------------------------------------------------------------
__global__ __launch_bounds__(256) void attn_kernel(
    const float* __restrict__ qkv, float* __restrict__ o) {
  int bh = blockIdx.y;
  int b = bh >> 3, hh = bh & 7;
  const float* qp = qkv + ((size_t)(b * 768 + hh * 96)) * L_;
  const float* kp = qp + 32 * L_;
  const float* vp = qp + 64 * L_;
  float* op = o + ((size_t)(b * 256 + hh * 32)) * L_;
  int l0 = blockIdx.x * 64;
  int t = threadIdx.x;

  __shared__ float qs[8][32];
  __shared__ float p[8][1024];    // 32 KB score/prob tile
  __shared__ float rowmax[8];
  __shared__ float rowsum[8];

  for (int pass = 0; pass < 8; ++pass) {
    int r0 = l0 + pass * 8;
    {
      int r = t >> 5, d = t & 31;
      qs[r][d] = qp[(size_t)d * L_ + r0 + r];
    }
    __syncthreads();

    // S = Q^T K / 16 for 8 rows x 1024 cols
    float sacc[8][4];
#pragma unroll
    for (int r = 0; r < 8; ++r)
#pragma unroll
      for (int c = 0; c < 4; ++c) sacc[r][c] = 0.f;
    for (int d = 0; d < 32; ++d) {
      float kk[4];
#pragma unroll
      for (int c = 0; c < 4; ++c) kk[c] = kp[(size_t)d * L_ + t + 256 * c];
#pragma unroll
      for (int r = 0; r < 8; ++r) {
        float qv = qs[r][d];
#pragma unroll
        for (int c = 0; c < 4; ++c) sacc[r][c] += qv * kk[c];
      }
    }
#pragma unroll
    for (int r = 0; r < 8; ++r)
#pragma unroll
      for (int c = 0; c < 4; ++c) p[r][t + 256 * c] = sacc[r][c] * 0.0625f;
    __syncthreads();

    // per-row max (32-lane group per row)
    {
      int g = t >> 5, lane = t & 31;
      float m = -1e30f;
      for (int i = 0; i < 32; ++i) m = fmaxf(m, p[g][lane + 32 * i]);
#pragma unroll
      for (int off = 16; off >= 1; off >>= 1) m = fmaxf(m, __shfl_xor(m, off));
      if (lane == 0) rowmax[g] = m;
    }
    __syncthreads();

    // exp in place
#pragma unroll
    for (int r = 0; r < 8; ++r) {
      float m = rowmax[r];
#pragma unroll
      for (int c = 0; c < 4; ++c) {
        int j = t + 256 * c;
        p[r][j] = expf(p[r][j] - m);
      }
    }
    __syncthreads();

    // per-row sum
    {
      int g = t >> 5, lane = t & 31;
      float sm = 0.f;
      for (int i = 0; i < 32; ++i) sm += p[g][lane + 32 * i];
#pragma unroll
      for (int off = 16; off >= 1; off >>= 1) sm += __shfl_xor(sm, off);
      if (lane == 0) rowsum[g] = sm;
    }
    __syncthreads();

    // O: thread = (r = t>>5, d = t&31), dot(p[r], v[d]) over 1024
    {
      int r = t >> 5, d = t & 31;
      const float* vd = vp + (size_t)d * L_;
      float acc = 0.f;
      for (int j = 0; j < 1024; j += 4) {
        float4 pv = *(const float4*)&p[r][j];
        float4 vv = *(const float4*)&vd[j];
        acc += pv.x * vv.x + pv.y * vv.y + pv.z * vv.z + pv.w * vv.w;
      }
      op[(size_t)d * L_ + r0 + r] = acc / rowsum[r];
    }
    __syncthreads();
  }
}

// ---------------------------------------------------------------------------
extern "C" void kernel_launch(void* const* d_in, const int* in_sizes, int n_in,
                              void* d_out, int out_size, void* d_ws, size_t ws_size,
                              hipStream_t stream) {
  const float* x      = (const float*)d_in[0];
  const float* gamma  = (const float*)d_in[1];
  const float* beta   = (const float*)d_in[2];
  const float* dw     = (const float*)d_in[3];
  const float* qkv_w  = (const float*)d_in[4];
  const float* qkv_b  = (const float*)d_in[5];
  const float* out_w  = (const float*)d_in[6];
  const float* out_b  = (const float*)d_in[7];
  float* out = (float*)d_out;

  float* h   = (float*)d_ws;                          // 8 MiB
  float* qkv = (float*)((char*)d_ws + (8u << 20));    // 24 MiB
  float* o   = h;                                     // reuse (h dead after qkv)

  gn_dwconv_kernel<<<B_ * 32, 256, 0, stream>>>(x, gamma, beta, dw, h);
  pconv_kernel<false><<<dim3(4, 12, B_), 256, 0, stream>>>(h, qkv_w, qkv_b, nullptr, qkv, 768);
  attn_kernel<<<dim3(16, B_ * NH_), 256, 0, stream>>>(qkv, o);
  pconv_kernel<true><<<dim3(4, 4, B_), 256, 0, stream>>>(o, out_w, out_b, x, out, 256);
}

// Round 2
// 211.124 us; speedup vs baseline: 5.3245x; 5.3245x over previous
//
#include <hip/hip_runtime.h>
#include <hip/hip_bf16.h>

#define B_ 8
#define C_ 256
#define L_ 1024
#define NH_ 8
#define EPS_ 1e-5f

typedef __attribute__((ext_vector_type(8))) short bf16x8;
typedef __attribute__((ext_vector_type(4))) float f32x4;

// ---------------------------------------------------------------------------
// Kernel A: GroupNorm (32 groups of 8 channels) + depthwise conv1d k=3 pad=1
// ---------------------------------------------------------------------------
__global__ __launch_bounds__(256) void gn_dwconv_kernel(
    const float* __restrict__ x, const float* __restrict__ gamma,
    const float* __restrict__ beta, const float* __restrict__ dw,
    float* __restrict__ h) {
  int blk = blockIdx.x;           // b*32 + g
  int b = blk >> 5, g = blk & 31;
  int t = threadIdx.x;
  __shared__ float hn[8 * L_];
  __shared__ float ws0[4], ws1[4];
  const size_t base = ((size_t)(b * C_ + g * 8)) * L_;

  float s = 0.f, ss = 0.f;
  float vals[32];
#pragma unroll
  for (int i = 0; i < 32; ++i) {
    int e = t + 256 * i;
    float v = x[base + e];
    vals[i] = v;
    s += v; ss += v * v;
  }
#pragma unroll
  for (int off = 32; off >= 1; off >>= 1) {
    s  += __shfl_xor(s, off);
    ss += __shfl_xor(ss, off);
  }
  int wave = t >> 6;
  if ((t & 63) == 0) { ws0[wave] = s; ws1[wave] = ss; }
  __syncthreads();
  s  = ws0[0] + ws0[1] + ws0[2] + ws0[3];
  ss = ws1[0] + ws1[1] + ws1[2] + ws1[3];
  float mean = s * (1.f / 8192.f);
  float var = ss * (1.f / 8192.f) - mean * mean;
  float rstd = rsqrtf(var + EPS_);

#pragma unroll
  for (int i = 0; i < 32; ++i) {
    int e = t + 256 * i;
    int c = g * 8 + (e >> 10);
    float sc = gamma[c] * rstd;
    hn[e] = (vals[i] - mean) * sc + beta[c];
  }
  __syncthreads();
#pragma unroll
  for (int i = 0; i < 32; ++i) {
    int e = t + 256 * i;
    int l = e & 1023;
    int c = g * 8 + (e >> 10);
    float w0 = dw[c * 3 + 0], w1 = dw[c * 3 + 1], w2 = dw[c * 3 + 2];
    float a = (l > 0) ? hn[e - 1] : 0.f;
    float m = hn[e];
    float z = (l < 1023) ? hn[e + 1] : 0.f;
    h[base + e] = w0 * a + w1 * m + w2 * z;
  }
}

// ---------------------------------------------------------------------------
// Kernel B/D: pointwise conv (1x1), fp32 GEMM. Optional bf16 output.
// ---------------------------------------------------------------------------
template <bool RESID, bool BF16OUT>
__global__ __launch_bounds__(256) void pconv_kernel(
    const float* __restrict__ in, const float* __restrict__ W,
    const float* __restrict__ bias, const float* __restrict__ resid,
    void* __restrict__ outv, int OC) {
  int b = blockIdx.z;
  int oc0 = blockIdx.y * 64;
  int l0 = blockIdx.x * 256;
  int t = threadIdx.x;
  int og = t >> 6, lt = t & 63;
  __shared__ float wsT[64][68];

  float acc[16][4];
#pragma unroll
  for (int i = 0; i < 16; ++i)
#pragma unroll
    for (int k = 0; k < 4; ++k) acc[i][k] = 0.f;

  const float* inb = in + (size_t)b * 256 * L_ + l0 + lt;

  for (int c0 = 0; c0 < 256; c0 += 64) {
    __syncthreads();
    for (int id = t; id < 4096; id += 256) {
      int cc = id & 63, ocl = id >> 6;
      wsT[cc][ocl] = W[(size_t)(oc0 + ocl) * 256 + c0 + cc];
    }
    __syncthreads();
    for (int cc = 0; cc < 64; ++cc) {
      float hv[4];
#pragma unroll
      for (int k = 0; k < 4; ++k) hv[k] = inb[(size_t)(c0 + cc) * L_ + 64 * k];
      float wv[16];
      *(float4*)&wv[0]  = *(const float4*)&wsT[cc][og * 16 + 0];
      *(float4*)&wv[4]  = *(const float4*)&wsT[cc][og * 16 + 4];
      *(float4*)&wv[8]  = *(const float4*)&wsT[cc][og * 16 + 8];
      *(float4*)&wv[12] = *(const float4*)&wsT[cc][og * 16 + 12];
#pragma unroll
      for (int i = 0; i < 16; ++i)
#pragma unroll
        for (int k = 0; k < 4; ++k) acc[i][k] += wv[i] * hv[k];
    }
  }

#pragma unroll
  for (int i = 0; i < 16; ++i) {
    int oc = oc0 + og * 16 + i;
    float bs = bias[oc];
    size_t ob = ((size_t)b * OC + oc) * L_ + l0 + lt;
#pragma unroll
    for (int k = 0; k < 4; ++k) {
      float r = acc[i][k] + bs;
      if (RESID) r += resid[ob + 64 * k];
      if (BF16OUT) {
        union { __hip_bfloat16 bf; ushort u; } cv;
        cv.bf = __float2bfloat16(r);
        ((ushort*)outv)[ob + 64 * k] = cv.u;
      } else {
        ((float*)outv)[ob + 64 * k] = r;
      }
    }
  }
}

// ---------------------------------------------------------------------------
// Repack: qkvb [B,768,L] bf16 -> qt,kt [bh][L][32] (transposed), vb [bh][32][L]
// grid (4 ltiles, 3 kinds, 64 bh)
// ---------------------------------------------------------------------------
__global__ __launch_bounds__(256) void repack_kernel(
    const ushort* __restrict__ qkvb, ushort* __restrict__ qt,
    ushort* __restrict__ kt, ushort* __restrict__ vb) {
  int l0 = blockIdx.x * 256;
  int kind = blockIdx.y;
  int bh = blockIdx.z;
  int b = bh >> 3, hh = bh & 7;
  int t = threadIdx.x;
  const ushort* src = qkvb + ((size_t)(b * 768 + hh * 96 + kind * 32)) * L_;
  int colu = t & 127, rhalf = t >> 7;

  if (kind == 2) {
    const uint* su = (const uint*)src;
    uint* du = (uint*)(vb + (size_t)bh * 32 * L_);
#pragma unroll
    for (int it = 0; it < 16; ++it) {
      int d = it * 2 + rhalf;
      int idx = d * 512 + l0 / 2 + colu;
      du[idx] = su[idx];
    }
  } else {
    __shared__ ushort tile[32][264];
    const uint* su = (const uint*)src;
#pragma unroll
    for (int it = 0; it < 16; ++it) {
      int d = it * 2 + rhalf;
      uint v = su[d * 512 + l0 / 2 + colu];
      tile[d][2 * colu] = (ushort)(v & 0xffff);
      tile[d][2 * colu + 1] = (ushort)(v >> 16);
    }
    __syncthreads();
    ushort* dst = (kind ? kt : qt) + (size_t)bh * L_ * 32;
    uint outv[16];
#pragma unroll
    for (int d2 = 0; d2 < 16; ++d2)
      outv[d2] = (uint)tile[2 * d2][t] | ((uint)tile[2 * d2 + 1][t] << 16);
    uint4* dp = (uint4*)(dst + (size_t)(l0 + t) * 32);
    dp[0] = make_uint4(outv[0], outv[1], outv[2], outv[3]);
    dp[1] = make_uint4(outv[4], outv[5], outv[6], outv[7]);
    dp[2] = make_uint4(outv[8], outv[9], outv[10], outv[11]);
    dp[3] = make_uint4(outv[12], outv[13], outv[14], outv[15]);
  }
}

// ---------------------------------------------------------------------------
// Kernel C: MFMA flash attention. Block = 4 waves, each wave 32 q rows.
// grid (8 qtiles, 64 bh). Swapped QK^T (S^T = K^T.Q); P stays in registers;
// PV permutation absorbed into V addressing.
// ---------------------------------------------------------------------------
__global__ __launch_bounds__(256) void attn_mfma_kernel(
    const ushort* __restrict__ qt, const ushort* __restrict__ kt,
    const ushort* __restrict__ vb, float* __restrict__ o) {
  const int bh = blockIdx.y;
  const int b = bh >> 3, hh = bh & 7;
  const int t = threadIdx.x;
  const int w = t >> 6;
  const int l = t & 63;
  const int g = l >> 4, ln = l & 15;
  const int q0 = blockIdx.x * 128 + w * 32;

  const ushort* qbase = qt + (size_t)bh * L_ * 32;
  const ushort* kbase = kt + (size_t)bh * L_ * 32;
  const ushort* vbase = vb + (size_t)bh * 32 * L_;

  const f32x4 z4 = {0.f, 0.f, 0.f, 0.f};

  // Q fragments (B operand): b[j] = Q[d=g*8+j][q=16*nq+ln]
  bf16x8 bq[2];
  bq[0] = *(const bf16x8*)(qbase + (size_t)(q0 + ln) * 32 + g * 8);
  bq[1] = *(const bf16x8*)(qbase + (size_t)(q0 + 16 + ln) * 32 + g * 8);

  f32x4 oacc[2][2];  // [md][nq]
  oacc[0][0] = z4; oacc[0][1] = z4; oacc[1][0] = z4; oacc[1][1] = z4;
  float M[2] = {-3e38f, -3e38f};
  float Ls[2] = {0.f, 0.f};
  const float c = 0.0625f * 1.44269504f;  // scale * log2(e)

  for (int kv0 = 0; kv0 < L_; kv0 += 64) {
    // S^T tile: A = K^T frag (a[j] = K[d=g*8+j][kv=16*mk+ln])
    f32x4 sacc[4][2];
#pragma unroll
    for (int mk = 0; mk < 4; ++mk) {
      bf16x8 ak = *(const bf16x8*)(kbase + (size_t)(kv0 + mk * 16 + ln) * 32 + g * 8);
      sacc[mk][0] = __builtin_amdgcn_mfma_f32_16x16x32_bf16(ak, bq[0], z4, 0, 0, 0);
      sacc[mk][1] = __builtin_amdgcn_mfma_f32_16x16x32_bf16(ak, bq[1], z4, 0, 0, 0);
    }

    // online softmax per nq; lane holds S^T[kv=16mk+g*4+r][q=16nq+ln]
    uint upk[2][4][2];
#pragma unroll
    for (int nq = 0; nq < 2; ++nq) {
      float mt = -3e38f;
#pragma unroll
      for (int mk = 0; mk < 4; ++mk)
#pragma unroll
        for (int r = 0; r < 4; ++r) mt = fmaxf(mt, sacc[mk][nq][r]);
      mt = fmaxf(mt, __shfl_xor(mt, 16));
      mt = fmaxf(mt, __shfl_xor(mt, 32));
      float Mn = fmaxf(M[nq], mt);
      float corr = exp2f((M[nq] - Mn) * c);
      M[nq] = Mn;
      float ts = 0.f;
      float pe[4][4];
#pragma unroll
      for (int mk = 0; mk < 4; ++mk)
#pragma unroll
        for (int r = 0; r < 4; ++r) {
          pe[mk][r] = exp2f((sacc[mk][nq][r] - Mn) * c);
          ts += pe[mk][r];
        }
      ts += __shfl_xor(ts, 16);
      ts += __shfl_xor(ts, 32);
      Ls[nq] = Ls[nq] * corr + ts;
#pragma unroll
      for (int md = 0; md < 2; ++md)
#pragma unroll
        for (int r = 0; r < 4; ++r) oacc[md][nq][r] *= corr;
      // pack P to bf16 pairs: upk[nq][mk][w] = (pe[2w], pe[2w+1])
#pragma unroll
      for (int mk = 0; mk < 4; ++mk) {
        uint u0, u1;
        asm("v_cvt_pk_bf16_f32 %0, %1, %2" : "=v"(u0) : "v"(pe[mk][0]), "v"(pe[mk][1]));
        asm("v_cvt_pk_bf16_f32 %0, %1, %2" : "=v"(u1) : "v"(pe[mk][2]), "v"(pe[mk][3]));
        upk[nq][mk][0] = u0;
        upk[nq][mk][1] = u1;
      }
    }

    // PV: A = V frag with permuted kv enumeration:
    // pos (g,j): kv = kv0 + 32ks + (j<4?0:16) + g*4 + (j&3)
#pragma unroll
    for (int md = 0; md < 2; ++md) {
      const ushort* vr = vbase + (size_t)(16 * md + ln) * L_ + kv0 + g * 4;
#pragma unroll
      for (int ks = 0; ks < 2; ++ks) {
        uint2 lo = *(const uint2*)(vr + 32 * ks);
        uint2 hi = *(const uint2*)(vr + 32 * ks + 16);
        union { uint u[4]; bf16x8 v; } av;
        av.u[0] = lo.x; av.u[1] = lo.y; av.u[2] = hi.x; av.u[3] = hi.y;
#pragma unroll
        for (int nq = 0; nq < 2; ++nq) {
          union { uint u[4]; bf16x8 v; } pb;
          pb.u[0] = upk[nq][2 * ks][0];
          pb.u[1] = upk[nq][2 * ks][1];
          pb.u[2] = upk[nq][2 * ks + 1][0];
          pb.u[3] = upk[nq][2 * ks + 1][1];
          oacc[md][nq] = __builtin_amdgcn_mfma_f32_16x16x32_bf16(av.v, pb.v, oacc[md][nq], 0, 0, 0);
        }
      }
    }
  }

  // epilogue: O[d][q], lane holds rows d=16md+g*4+r, col q=16nq+ln
#pragma unroll
  for (int nq = 0; nq < 2; ++nq) {
    float rl = 1.f / Ls[nq];
#pragma unroll
    for (int md = 0; md < 2; ++md)
#pragma unroll
      for (int r = 0; r < 4; ++r) {
        int d = 16 * md + g * 4 + r;
        o[((size_t)(b * 256 + hh * 32 + d)) * L_ + q0 + 16 * nq + ln] =
            oacc[md][nq][r] * rl;
      }
  }
}

// ---------------------------------------------------------------------------
extern "C" void kernel_launch(void* const* d_in, const int* in_sizes, int n_in,
                              void* d_out, int out_size, void* d_ws, size_t ws_size,
                              hipStream_t stream) {
  const float* x      = (const float*)d_in[0];
  const float* gamma  = (const float*)d_in[1];
  const float* beta   = (const float*)d_in[2];
  const float* dw     = (const float*)d_in[3];
  const float* qkv_w  = (const float*)d_in[4];
  const float* qkv_b  = (const float*)d_in[5];
  const float* out_w  = (const float*)d_in[6];
  const float* out_b  = (const float*)d_in[7];
  float* out = (float*)d_out;

  float*  h    = (float*)d_ws;                            // 8 MiB @0
  ushort* qkvb = (ushort*)((char*)d_ws + (8u << 20));     // 12 MiB @8
  ushort* qtb  = (ushort*)((char*)d_ws + (20u << 20));    // 4 MiB @20
  ushort* ktb  = (ushort*)((char*)d_ws + (24u << 20));    // 4 MiB @24
  ushort* vbb  = (ushort*)((char*)d_ws + (28u << 20));    // 4 MiB @28
  float*  o    = h;                                       // reuse (h dead)

  gn_dwconv_kernel<<<B_ * 32, 256, 0, stream>>>(x, gamma, beta, dw, h);
  pconv_kernel<false, true><<<dim3(4, 12, B_), 256, 0, stream>>>(
      h, qkv_w, qkv_b, nullptr, (void*)qkvb, 768);
  repack_kernel<<<dim3(4, 3, 64), 256, 0, stream>>>(qkvb, qtb, ktb, vbb);
  attn_mfma_kernel<<<dim3(8, 64), 256, 0, stream>>>(qtb, ktb, vbb, o);
  pconv_kernel<true, false><<<dim3(4, 4, B_), 256, 0, stream>>>(
      o, out_w, out_b, x, (void*)out, 256);
}

// Round 3
// 102.889 us; speedup vs baseline: 10.9257x; 2.0520x over previous
//
#include <hip/hip_runtime.h>
#include <hip/hip_bf16.h>

#define B_ 8
#define C_ 256
#define L_ 1024
#define NH_ 8
#define EPS_ 1e-5f

typedef __attribute__((ext_vector_type(8))) short bf16x8;
typedef __attribute__((ext_vector_type(4))) float f32x4;

static __device__ inline ushort f2bf(float f) {
  union { __hip_bfloat16 b; ushort u; } c;
  c.b = __float2bfloat16(f);
  return c.u;
}

// ---------------------------------------------------------------------------
// Kernel W: convert qkv_w [768,256] and out_w [256,256] fp32 -> bf16
// 65536 float4 total: 49152 qkv + 16384 out. grid 256 x 256.
// ---------------------------------------------------------------------------
__global__ __launch_bounds__(256) void wconv_kernel(
    const float4* __restrict__ qw, const float4* __restrict__ ow,
    uint2* __restrict__ wq, uint2* __restrict__ wo) {
  int id = blockIdx.x * 256 + threadIdx.x;
  float4 v;
  uint2* dst;
  if (id < 49152) { v = qw[id]; dst = wq + id; }
  else { v = ow[id - 49152]; dst = wo + (id - 49152); }
  union { ushort s[4]; uint2 u; } p;
  p.s[0] = f2bf(v.x); p.s[1] = f2bf(v.y); p.s[2] = f2bf(v.z); p.s[3] = f2bf(v.w);
  *dst = p.u;
}

// ---------------------------------------------------------------------------
// Kernel A: GroupNorm + depthwise conv k=3, output TRANSPOSED bf16 ht[B][L][256]
// block per (b, group of 8 ch)
// ---------------------------------------------------------------------------
__global__ __launch_bounds__(256) void gn_dwconv_kernel(
    const float* __restrict__ x, const float* __restrict__ gamma,
    const float* __restrict__ beta, const float* __restrict__ dw,
    ushort* __restrict__ ht) {
  int blk = blockIdx.x;           // b*32 + g
  int b = blk >> 5, g = blk & 31;
  int t = threadIdx.x;
  __shared__ float hn[8 * L_];
  __shared__ float ws0[4], ws1[4];
  const size_t base = ((size_t)(b * C_ + g * 8)) * L_;

  float s = 0.f, ss = 0.f;
  float vals[32];
#pragma unroll
  for (int i = 0; i < 32; ++i) {
    int e = t + 256 * i;
    float v = x[base + e];
    vals[i] = v;
    s += v; ss += v * v;
  }
#pragma unroll
  for (int off = 32; off >= 1; off >>= 1) {
    s  += __shfl_xor(s, off);
    ss += __shfl_xor(ss, off);
  }
  int wave = t >> 6;
  if ((t & 63) == 0) { ws0[wave] = s; ws1[wave] = ss; }
  __syncthreads();
  s  = ws0[0] + ws0[1] + ws0[2] + ws0[3];
  ss = ws1[0] + ws1[1] + ws1[2] + ws1[3];
  float mean = s * (1.f / 8192.f);
  float var = ss * (1.f / 8192.f) - mean * mean;
  float rstd = rsqrtf(var + EPS_);

#pragma unroll
  for (int i = 0; i < 32; ++i) {
    int e = t + 256 * i;
    int c = g * 8 + (e >> 10);
    float sc = gamma[c] * rstd;
    hn[e] = (vals[i] - mean) * sc + beta[c];
  }
  __syncthreads();
  // conv: thread t holds, for c_loc = i>>2, l = t + 256*(i&3)
  float r[32];
#pragma unroll
  for (int i = 0; i < 32; ++i) {
    int e = t + 256 * i;
    int l = e & 1023;
    int c = g * 8 + (i >> 2);
    float w0 = dw[c * 3 + 0], w1 = dw[c * 3 + 1], w2 = dw[c * 3 + 2];
    float a = (l > 0) ? hn[e - 1] : 0.f;
    float m = hn[e];
    float z = (l < 1023) ? hn[e + 1] : 0.f;
    r[i] = w0 * a + w1 * m + w2 * z;
  }
  // transposed write: for each of 4 l values, 8 channels contiguous (16B)
#pragma unroll
  for (int li = 0; li < 4; ++li) {
    int l = t + 256 * li;
    union { ushort s8[8]; uint4 u; } pk;
#pragma unroll
    for (int cl = 0; cl < 8; ++cl) pk.s8[cl] = f2bf(r[4 * cl + li]);
    *(uint4*)(ht + ((size_t)(b * L_ + l)) * 256 + g * 8) = pk.u;
  }
}

// ---------------------------------------------------------------------------
// Kernel B/D: pointwise conv via MFMA. M=l, N=oc, K=c(256).
// Xt: [B][L][256] bf16; Wb: [OC][256] bf16. out: [B][OC][L].
// Block 4 waves (2l x 2oc); wave tile 64l x OCT oc. grid (L/128, OC/(2*OCT), B)
// ---------------------------------------------------------------------------
template <bool RESID, bool BF16OUT, int OCT>
__global__ __launch_bounds__(256) void pconv_mfma_kernel(
    const ushort* __restrict__ Xt, const ushort* __restrict__ Wb,
    const float* __restrict__ bias, const float* __restrict__ resid,
    void* __restrict__ outv, int OC) {
  constexpr int NN = OCT / 16;
  int b = blockIdx.z;
  int t = threadIdx.x;
  int w = t >> 6, l = t & 63;
  int g = l >> 4, ln = l & 15;
  int wl = w >> 1, wo = w & 1;
  int lbase = blockIdx.x * 128 + wl * 64;
  int ocbase = blockIdx.y * (2 * OCT) + wo * OCT;

  const ushort* xp = Xt + ((size_t)b * L_ + lbase) * 256;
  const ushort* wp = Wb + (size_t)ocbase * 256;

  f32x4 acc[4][NN];
#pragma unroll
  for (int ml = 0; ml < 4; ++ml)
#pragma unroll
    for (int nn = 0; nn < NN; ++nn) acc[ml][nn] = (f32x4){0.f, 0.f, 0.f, 0.f};

  for (int c0 = 0; c0 < 256; c0 += 32) {
    bf16x8 af[4], bf[NN];
#pragma unroll
    for (int ml = 0; ml < 4; ++ml)
      af[ml] = *(const bf16x8*)(xp + (size_t)(16 * ml + ln) * 256 + c0 + 8 * g);
#pragma unroll
    for (int nn = 0; nn < NN; ++nn)
      bf[nn] = *(const bf16x8*)(wp + (size_t)(16 * nn + ln) * 256 + c0 + 8 * g);
#pragma unroll
    for (int ml = 0; ml < 4; ++ml)
#pragma unroll
      for (int nn = 0; nn < NN; ++nn)
        acc[ml][nn] = __builtin_amdgcn_mfma_f32_16x16x32_bf16(af[ml], bf[nn], acc[ml][nn], 0, 0, 0);
  }

#pragma unroll
  for (int nn = 0; nn < NN; ++nn) {
    int oc = ocbase + 16 * nn + ln;
    float bs = bias[oc];
#pragma unroll
    for (int ml = 0; ml < 4; ++ml) {
      int lr = lbase + 16 * ml + 4 * g;
      size_t ob = ((size_t)b * OC + oc) * L_ + lr;
      float rv[4];
#pragma unroll
      for (int r4 = 0; r4 < 4; ++r4) rv[r4] = acc[ml][nn][r4] + bs;
      if (RESID) {
        float4 rd = *(const float4*)(resid + ob);
        rv[0] += rd.x; rv[1] += rd.y; rv[2] += rd.z; rv[3] += rd.w;
      }
      if (BF16OUT) {
        union { ushort s[4]; uint2 u; } pk;
#pragma unroll
        for (int r4 = 0; r4 < 4; ++r4) pk.s[r4] = f2bf(rv[r4]);
        *(uint2*)((ushort*)outv + ob) = pk.u;
      } else {
        float4 st = make_float4(rv[0], rv[1], rv[2], rv[3]);
        *(float4*)((float*)outv + ob) = st;
      }
    }
  }
}

// ---------------------------------------------------------------------------
// Repack: qkvb [B,768,L] bf16 -> qt,kt [bh][L][32] (transposed), vb [bh][32][L]
// ---------------------------------------------------------------------------
__global__ __launch_bounds__(256) void repack_kernel(
    const ushort* __restrict__ qkvb, ushort* __restrict__ qt,
    ushort* __restrict__ kt, ushort* __restrict__ vb) {
  int l0 = blockIdx.x * 256;
  int kind = blockIdx.y;
  int bh = blockIdx.z;
  int b = bh >> 3, hh = bh & 7;
  int t = threadIdx.x;
  const ushort* src = qkvb + ((size_t)(b * 768 + hh * 96 + kind * 32)) * L_;
  int colu = t & 127, rhalf = t >> 7;

  if (kind == 2) {
    const uint* su = (const uint*)src;
    uint* du = (uint*)(vb + (size_t)bh * 32 * L_);
#pragma unroll
    for (int it = 0; it < 16; ++it) {
      int d = it * 2 + rhalf;
      int idx = d * 512 + l0 / 2 + colu;
      du[idx] = su[idx];
    }
  } else {
    __shared__ ushort tile[32][264];
    const uint* su = (const uint*)src;
#pragma unroll
    for (int it = 0; it < 16; ++it) {
      int d = it * 2 + rhalf;
      uint v = su[d * 512 + l0 / 2 + colu];
      tile[d][2 * colu] = (ushort)(v & 0xffff);
      tile[d][2 * colu + 1] = (ushort)(v >> 16);
    }
    __syncthreads();
    ushort* dst = (kind ? kt : qt) + (size_t)bh * L_ * 32;
    uint outv[16];
#pragma unroll
    for (int d2 = 0; d2 < 16; ++d2)
      outv[d2] = (uint)tile[2 * d2][t] | ((uint)tile[2 * d2 + 1][t] << 16);
    uint4* dp = (uint4*)(dst + (size_t)(l0 + t) * 32);
    dp[0] = make_uint4(outv[0], outv[1], outv[2], outv[3]);
    dp[1] = make_uint4(outv[4], outv[5], outv[6], outv[7]);
    dp[2] = make_uint4(outv[8], outv[9], outv[10], outv[11]);
    dp[3] = make_uint4(outv[12], outv[13], outv[14], outv[15]);
  }
}

// ---------------------------------------------------------------------------
// Kernel C: MFMA flash attention; output TRANSPOSED bf16 ot[B][L][256]
// ---------------------------------------------------------------------------
__global__ __launch_bounds__(256) void attn_mfma_kernel(
    const ushort* __restrict__ qt, const ushort* __restrict__ kt,
    const ushort* __restrict__ vb, ushort* __restrict__ ot) {
  const int bh = blockIdx.y;
  const int b = bh >> 3, hh = bh & 7;
  const int t = threadIdx.x;
  const int w = t >> 6;
  const int l = t & 63;
  const int g = l >> 4, ln = l & 15;
  const int q0b = blockIdx.x * 128;
  const int q0 = q0b + w * 32;

  const ushort* qbase = qt + (size_t)bh * L_ * 32;
  const ushort* kbase = kt + (size_t)bh * L_ * 32;
  const ushort* vbase = vb + (size_t)bh * 32 * L_;

  const f32x4 z4 = {0.f, 0.f, 0.f, 0.f};

  bf16x8 bq[2];
  bq[0] = *(const bf16x8*)(qbase + (size_t)(q0 + ln) * 32 + g * 8);
  bq[1] = *(const bf16x8*)(qbase + (size_t)(q0 + 16 + ln) * 32 + g * 8);

  f32x4 oacc[2][2];  // [md][nq]
  oacc[0][0] = z4; oacc[0][1] = z4; oacc[1][0] = z4; oacc[1][1] = z4;
  float M[2] = {-3e38f, -3e38f};
  float Ls[2] = {0.f, 0.f};
  const float c = 0.0625f * 1.44269504f;

  for (int kv0 = 0; kv0 < L_; kv0 += 64) {
    f32x4 sacc[4][2];
#pragma unroll
    for (int mk = 0; mk < 4; ++mk) {
      bf16x8 ak = *(const bf16x8*)(kbase + (size_t)(kv0 + mk * 16 + ln) * 32 + g * 8);
      sacc[mk][0] = __builtin_amdgcn_mfma_f32_16x16x32_bf16(ak, bq[0], z4, 0, 0, 0);
      sacc[mk][1] = __builtin_amdgcn_mfma_f32_16x16x32_bf16(ak, bq[1], z4, 0, 0, 0);
    }

    uint upk[2][4][2];
#pragma unroll
    for (int nq = 0; nq < 2; ++nq) {
      float mt = -3e38f;
#pragma unroll
      for (int mk = 0; mk < 4; ++mk)
#pragma unroll
        for (int r = 0; r < 4; ++r) mt = fmaxf(mt, sacc[mk][nq][r]);
      mt = fmaxf(mt, __shfl_xor(mt, 16));
      mt = fmaxf(mt, __shfl_xor(mt, 32));
      float Mn = fmaxf(M[nq], mt);
      float corr = exp2f((M[nq] - Mn) * c);
      M[nq] = Mn;
      float ts = 0.f;
      float pe[4][4];
#pragma unroll
      for (int mk = 0; mk < 4; ++mk)
#pragma unroll
        for (int r = 0; r < 4; ++r) {
          pe[mk][r] = exp2f((sacc[mk][nq][r] - Mn) * c);
          ts += pe[mk][r];
        }
      ts += __shfl_xor(ts, 16);
      ts += __shfl_xor(ts, 32);
      Ls[nq] = Ls[nq] * corr + ts;
#pragma unroll
      for (int md = 0; md < 2; ++md)
#pragma unroll
        for (int r = 0; r < 4; ++r) oacc[md][nq][r] *= corr;
#pragma unroll
      for (int mk = 0; mk < 4; ++mk) {
        uint u0, u1;
        asm("v_cvt_pk_bf16_f32 %0, %1, %2" : "=v"(u0) : "v"(pe[mk][0]), "v"(pe[mk][1]));
        asm("v_cvt_pk_bf16_f32 %0, %1, %2" : "=v"(u1) : "v"(pe[mk][2]), "v"(pe[mk][3]));
        upk[nq][mk][0] = u0;
        upk[nq][mk][1] = u1;
      }
    }

#pragma unroll
    for (int md = 0; md < 2; ++md) {
      const ushort* vr = vbase + (size_t)(16 * md + ln) * L_ + kv0 + g * 4;
#pragma unroll
      for (int ks = 0; ks < 2; ++ks) {
        uint2 lo = *(const uint2*)(vr + 32 * ks);
        uint2 hi = *(const uint2*)(vr + 32 * ks + 16);
        union { uint u[4]; bf16x8 v; } av;
        av.u[0] = lo.x; av.u[1] = lo.y; av.u[2] = hi.x; av.u[3] = hi.y;
#pragma unroll
        for (int nq = 0; nq < 2; ++nq) {
          union { uint u[4]; bf16x8 v; } pb;
          pb.u[0] = upk[nq][2 * ks][0];
          pb.u[1] = upk[nq][2 * ks][1];
          pb.u[2] = upk[nq][2 * ks + 1][0];
          pb.u[3] = upk[nq][2 * ks + 1][1];
          oacc[md][nq] = __builtin_amdgcn_mfma_f32_16x16x32_bf16(av.v, pb.v, oacc[md][nq], 0, 0, 0);
        }
      }
    }
  }

  // epilogue: LDS transpose -> ot[B][L][256] bf16, coalesced 64B rows
  __shared__ __align__(16) ushort ot_tile[128][40];
#pragma unroll
  for (int nq = 0; nq < 2; ++nq) {
    float rl = 1.f / Ls[nq];
    int q_loc = w * 32 + 16 * nq + ln;
#pragma unroll
    for (int md = 0; md < 2; ++md) {
      int d0 = 16 * md + 4 * g;
      ushort4 pk;
      pk.x = f2bf(oacc[md][nq][0] * rl);
      pk.y = f2bf(oacc[md][nq][1] * rl);
      pk.z = f2bf(oacc[md][nq][2] * rl);
      pk.w = f2bf(oacc[md][nq][3] * rl);
      *(ushort4*)&ot_tile[q_loc][d0] = pk;
    }
  }
  __syncthreads();
  {
    int q_loc = t >> 1, half = t & 1;
    const uint4* srcp = (const uint4*)&ot_tile[q_loc][half * 16];
    uint4 v0 = srcp[0], v1 = srcp[1];
    ushort* dstp = ot + ((size_t)(b * L_ + q0b + q_loc)) * 256 + hh * 32 + half * 16;
    *(uint4*)dstp = v0;
    *(uint4*)(dstp + 8) = v1;
  }
}

// ---------------------------------------------------------------------------
extern "C" void kernel_launch(void* const* d_in, const int* in_sizes, int n_in,
                              void* d_out, int out_size, void* d_ws, size_t ws_size,
                              hipStream_t stream) {
  const float* x      = (const float*)d_in[0];
  const float* gamma  = (const float*)d_in[1];
  const float* beta   = (const float*)d_in[2];
  const float* dw     = (const float*)d_in[3];
  const float* qkv_w  = (const float*)d_in[4];
  const float* qkv_b  = (const float*)d_in[5];
  const float* out_w  = (const float*)d_in[6];
  const float* out_b  = (const float*)d_in[7];
  float* out = (float*)d_out;

  char* ws = (char*)d_ws;
  ushort* ht   = (ushort*)(ws);                   // 4 MiB @0  (dead after qkv)
  ushort* qkvb = (ushort*)(ws + (4u << 20));      // 12 MiB @4 (dead after repack)
  ushort* qtb  = (ushort*)(ws + (16u << 20));     // 4 MiB @16
  ushort* ktb  = (ushort*)(ws + (20u << 20));     // 4 MiB @20
  ushort* vbb  = (ushort*)(ws + (24u << 20));     // 4 MiB @24
  ushort* otb  = (ushort*)(ws);                   // 4 MiB @0  (reuse ht)
  ushort* wq   = (ushort*)(ws + (28u << 20));     // 384 KiB @28M
  ushort* wo   = (ushort*)(ws + (28u << 20) + (512u << 10));  // 128 KiB

  wconv_kernel<<<256, 256, 0, stream>>>((const float4*)qkv_w, (const float4*)out_w,
                                        (uint2*)wq, (uint2*)wo);
  gn_dwconv_kernel<<<B_ * 32, 256, 0, stream>>>(x, gamma, beta, dw, ht);
  pconv_mfma_kernel<false, true, 64><<<dim3(8, 6, B_), 256, 0, stream>>>(
      ht, wq, qkv_b, nullptr, (void*)qkvb, 768);
  repack_kernel<<<dim3(4, 3, 64), 256, 0, stream>>>(qkvb, qtb, ktb, vbb);
  attn_mfma_kernel<<<dim3(8, 64), 256, 0, stream>>>(qtb, ktb, vbb, otb);
  pconv_mfma_kernel<true, false, 32><<<dim3(8, 4, B_), 256, 0, stream>>>(
      otb, wo, out_b, x, (void*)out, 256);
}